// Round 9
// baseline (258.380 us; speedup 1.0000x reference)
//
#include <hip/hip_runtime.h>

#define BQ 2048
#define MM 65536
#define CC 128
#define QBS 128                 // queries per attn block
#define NQB2 (BQ/QBS)           // 16
#define NSPLIT 64
#define KCHUNK (MM/NSPLIT)      // 1024
#define NBUCKET 1024

typedef short short8 __attribute__((ext_vector_type(8)));
typedef float f32x4 __attribute__((ext_vector_type(4)));
typedef unsigned int u32x4 __attribute__((ext_vector_type(4)));
typedef unsigned int u32;

__device__ __forceinline__ unsigned short f2bf(float x) {
    unsigned int u = __builtin_bit_cast(unsigned int, x);
    u = (u + 0x7FFFu + ((u >> 16) & 1u)) >> 16;
    return (unsigned short)u;
}
__device__ __forceinline__ float bf2f(unsigned short u) {
    return __builtin_bit_cast(float, (unsigned int)u << 16);
}
__device__ __forceinline__ int bucket_of(float v) {
    return (int)fminf(fmaxf(v * 1024.0f, 0.0f), 1023.0f);
}
__device__ __forceinline__ u32 cvtpk(float lo, float hi) {
    u32 r;
    asm("v_cvt_pk_bf16_f32 %0, %1, %2" : "=v"(r) : "v"(lo), "v"(hi));
    return r;
}

// ---------------- exact query rank by seed_time (parallel, deterministic) -------------
__global__ __launch_bounds__(256) void qrank_kernel(
    const float* __restrict__ seed, int* __restrict__ qperm,
    int* __restrict__ qrank, float* __restrict__ seed_s)
{
    int t = threadIdx.x;
    int q = blockIdx.x*8 + (t >> 5);
    int l32 = t & 31;
    float v = seed[q];
    int r = 0;
    for (int seg = 0; seg < 64; ++seg) {
        int j = seg*32 + l32;
        float u = seed[j];
        r += (u < v) || (u == v && j < q);
    }
    #pragma unroll
    for (int m2 = 1; m2 < 32; m2 <<= 1) r += __shfl_xor(r, m2, 32);
    if (l32 == 0) { qperm[r] = q; qrank[q] = r; seed_s[r] = v; }
}

// ---------------- counting sort of memory keys by mst ---------------------------------
__global__ __launch_bounds__(256) void sort_hist_kernel(
    const float* __restrict__ mst, unsigned int* __restrict__ histT)
{
    __shared__ unsigned int h[NBUCKET];
    int t = threadIdx.x, b = blockIdx.x;
    #pragma unroll
    for (int j = t; j < NBUCKET; j += 256) h[j] = 0;
    __syncthreads();
    int bin = bucket_of(mst[b*256 + t]);
    atomicAdd(&h[bin], 1u);
    __syncthreads();
    #pragma unroll
    for (int j = t; j < NBUCKET; j += 256) histT[(size_t)j*256 + b] = h[j];
}

__global__ __launch_bounds__(64) void sort_scanA_kernel(
    unsigned int* __restrict__ histT, unsigned int* __restrict__ btot)
{
    int j = blockIdx.x;
    int t = threadIdx.x;
    uint4 v = *(uint4*)(histT + (size_t)j*256 + t*4);
    unsigned int s0 = v.x, s1 = v.y, s2 = v.z, s3 = v.w;
    unsigned int tsum = s0 + s1 + s2 + s3;
    unsigned int inc = tsum;
    #pragma unroll
    for (int off = 1; off < 64; off <<= 1) {
        unsigned int n = __shfl_up(inc, off, 64);
        if (t >= off) inc += n;
    }
    unsigned int ex = inc - tsum;
    uint4 o;
    o.x = ex; o.y = ex + s0; o.z = ex + s0 + s1; o.w = ex + s0 + s1 + s2;
    *(uint4*)(histT + (size_t)j*256 + t*4) = o;
    if (t == 63) btot[j] = inc;
}

__global__ __launch_bounds__(1024) void sort_scanB_kernel(
    const unsigned int* __restrict__ btot, unsigned int* __restrict__ gbase)
{
    __shared__ unsigned int sc[NBUCKET];
    int j = threadIdx.x;
    unsigned int tot = btot[j];
    sc[j] = tot;
    __syncthreads();
    for (int off = 1; off < NBUCKET; off <<= 1) {
        unsigned int y = (j >= off) ? sc[j - off] : 0u;
        __syncthreads();
        sc[j] += y;
        __syncthreads();
    }
    gbase[j] = sc[j] - tot;
}

__global__ __launch_bounds__(256) void sort_scatter_kernel(
    const float* __restrict__ mst, const unsigned int* __restrict__ histT,
    const unsigned int* __restrict__ gbase,
    int* __restrict__ dperm, float* __restrict__ mst_s)
{
    __shared__ int bins[256];
    int t = threadIdx.x, b = blockIdx.x;
    int i = b*256 + t;
    float v = mst[i];
    int bin = bucket_of(v);
    bins[t] = bin;
    __syncthreads();
    int pos = 0;
    for (int j = 0; j < t; ++j) pos += (bins[j] == bin);
    unsigned int dest = gbase[bin] + histT[(size_t)bin*256 + b] + pos;
    dperm[dest] = i;
    mst_s[dest] = v;
}

// ---------------- exact intra-bucket sort (value, orig idx) ---------------------------
__global__ __launch_bounds__(64) void sortfix_kernel(
    float* __restrict__ mst_s, int* __restrict__ dperm,
    const unsigned int* __restrict__ gbase, const unsigned int* __restrict__ btot)
{
    __shared__ float vals[512];
    __shared__ int idxs[512];
    int b = blockIdx.x;
    int base = (int)gbase[b];
    int n = (int)btot[b];
    if (n > 512) n = 512;
    if (n <= 1) return;
    int t = threadIdx.x;
    for (int i = t; i < n; i += 64) { vals[i] = mst_s[base + i]; idxs[i] = dperm[base + i]; }
    __syncthreads();
    for (int i = t; i < n; i += 64) {
        float v = vals[i]; int d = idxs[i];
        int rank = 0;
        for (int j = 0; j < n; ++j) {
            float vj = vals[j];
            rank += (vj < v) || (vj == v && idxs[j] < d);
        }
        mst_s[base + rank] = v;
        dperm[base + rank] = d;
    }
}

// ---------------- exact cut position per sorted query row -----------------------------
__global__ __launch_bounds__(256) void cq_kernel(
    const float* __restrict__ seed_s, const float* __restrict__ mst_s,
    const unsigned int* __restrict__ gbase, const unsigned int* __restrict__ btot,
    int* __restrict__ cq)
{
    int r = blockIdx.x*256 + threadIdx.x;
    float s = seed_s[r];
    int b = bucket_of(s);
    int base = (int)gbase[b];
    int n = (int)btot[b];
    int cnt = 0;
    for (int i = 0; i < n; ++i) cnt += (mst_s[base + i] <= s) ? 1 : 0;
    cq[r] = base + cnt;
}

// ---------------- memory l2norm (gathered) -> xhat + xhatT(130 rows incl y, ones) -----
__global__ __launch_bounds__(256) void mem_norm_kernel(
    const float* __restrict__ mx, const int* __restrict__ dperm,
    const int* __restrict__ memy,
    unsigned short* __restrict__ xhat, unsigned short* __restrict__ xhatT)
{
    __shared__ __align__(16) unsigned short tile[128*132];  // bf16, stride 132
    __shared__ float rs[128];
    __shared__ float invn[128];
    __shared__ int operm[128];
    const int t = threadIdx.x;
    const int kb0 = blockIdx.x * 128;

    if (t < 128) operm[t] = dperm[kb0 + t];
    __syncthreads();

    float4 vals[16];
    #pragma unroll
    for (int i = 0; i < 16; ++i) {
        int f4 = t + 256*i;
        int row = f4 >> 5, col4 = f4 & 31;
        float4 v = *(const float4*)(mx + (size_t)operm[row]*CC + col4*4);
        vals[i] = v;
        float s = v.x*v.x + v.y*v.y + v.z*v.z + v.w*v.w;
        #pragma unroll
        for (int m2 = 1; m2 < 32; m2 <<= 1) s += __shfl_xor(s, m2, 64);
        if ((t & 31) == 0) rs[row] = s;
    }
    __syncthreads();
    if (t < 128) invn[t] = 1.0f / fmaxf(sqrtf(rs[t]), 1e-12f);
    __syncthreads();
    #pragma unroll
    for (int i = 0; i < 16; ++i) {
        int f4 = t + 256*i;
        int row = f4 >> 5, col4 = f4 & 31;
        float sc = invn[row];
        float4 v = vals[i];
        ushort4 o;
        o.x = f2bf(v.x*sc); o.y = f2bf(v.y*sc); o.z = f2bf(v.z*sc); o.w = f2bf(v.w*sc);
        *(ushort4*)&tile[row*132 + col4*4] = o;
    }
    __syncthreads();
    #pragma unroll
    for (int i = 0; i < 8; ++i) {
        int u = t + 256*i;
        int row = u >> 4, c8 = u & 15;
        ushort4 a0 = *(ushort4*)&tile[row*132 + c8*8];
        ushort4 a1 = *(ushort4*)&tile[row*132 + c8*8 + 4];
        *(ushort4*)(xhat + (size_t)(kb0 + row)*CC + c8*8) = a0;
        *(ushort4*)(xhat + (size_t)(kb0 + row)*CC + c8*8 + 4) = a1;
    }
    #pragma unroll
    for (int i = 0; i < 8; ++i) {
        int u = t + 256*i;
        int c = u >> 4, k8 = u & 15;
        ushort4 o0, o1;
        o0.x = tile[(k8*8+0)*132 + c]; o0.y = tile[(k8*8+1)*132 + c];
        o0.z = tile[(k8*8+2)*132 + c]; o0.w = tile[(k8*8+3)*132 + c];
        o1.x = tile[(k8*8+4)*132 + c]; o1.y = tile[(k8*8+5)*132 + c];
        o1.z = tile[(k8*8+6)*132 + c]; o1.w = tile[(k8*8+7)*132 + c];
        *(ushort4*)(xhatT + (size_t)c*MM + kb0 + k8*8) = o0;
        *(ushort4*)(xhatT + (size_t)c*MM + kb0 + k8*8 + 4) = o1;
    }
    // stats rows only: 128 = y (bf16 exact), 129 = 1.0 (coalesced 256B runs)
    if (t < 128) {
        float yv = (float)memy[operm[t]];
        xhatT[(size_t)128*MM + kb0 + t] = f2bf(yv);
        xhatT[(size_t)129*MM + kb0 + t] = 0x3F80;
    }
}

// ---------------- query prep (+ etab fold): q2 = (l2norm(f)@Kw + kb)@Kw^T * log2e -----
__global__ __launch_bounds__(256) void query_prep_kernel(
    const float* __restrict__ feat, const float* __restrict__ keyw,
    const float* __restrict__ keyb, const float* __restrict__ msgw,
    const float* __restrict__ msgb, const float* __restrict__ yemb,
    const int* __restrict__ qrank,
    unsigned short* __restrict__ q2, float* __restrict__ a,
    float* __restrict__ etab)
{
    __shared__ float fl[4][128], t1[4][128];
    const int t = threadIdx.x;
    if (blockIdx.x == BQ/4) {
        if (t < 128) {
            float acc0 = msgb[t], acc1 = msgb[t];
            for (int c2 = 0; c2 < 128; ++c2) {
                float w3 = msgw[(256 + c2)*128 + t];
                acc0 = fmaf(yemb[c2], w3, acc0);
                acc1 = fmaf(yemb[128 + c2], w3, acc1);
            }
            etab[t] = acc0;
            etab[128 + t] = acc1;
        }
        return;
    }
    const int w = t >> 6;
    const int lane = t & 63;
    const int b = blockIdx.x*4 + w;
    const int j0 = lane, j1 = lane + 64;
    float f0 = feat[b*CC + j0], f1 = feat[b*CC + j1];
    fl[w][j0] = f0; fl[w][j1] = f1;
    float s = f0*f0 + f1*f1;
    #pragma unroll
    for (int m2 = 1; m2 < 64; m2 <<= 1) s += __shfl_xor(s, m2, 64);
    float invn = 1.0f / fmaxf(sqrtf(s), 1e-12f);
    __syncthreads();
    float g0 = 0.f, g1 = 0.f, a0 = 0.f, a1 = 0.f;
    for (int i = 0; i < 128; ++i) {
        float x = fl[w][i];
        g0 = fmaf(x, keyw[i*128 + j0], g0);
        g1 = fmaf(x, keyw[i*128 + j1], g1);
        a0 = fmaf(x, msgw[i*128 + j0], a0);
        a1 = fmaf(x, msgw[i*128 + j1], a1);
    }
    t1[w][j0] = g0*invn + keyb[j0];
    t1[w][j1] = g1*invn + keyb[j1];
    a[b*CC + j0] = a0;
    a[b*CC + j1] = a1;
    __syncthreads();
    float q0 = 0.f, q1 = 0.f;
    for (int c2 = 0; c2 < 128; ++c2) {
        float u = t1[w][c2];
        q0 = fmaf(u, keyw[j0*128 + c2], q0);
        q1 = fmaf(u, keyw[j1*128 + c2], q1);
    }
    const float LOG2E = 1.4426950408889634f;
    int rb = qrank[b];
    q2[rb*CC + j0] = f2bf(q0 * LOG2E);
    q2[rb*CC + j1] = f2bf(q1 * LOG2E);
}

// ---------------- flash attention: 128-q blocks, swapped MFMA, in-lane P --------------
// Each wave owns TWO 16-q strips (qlocal = w*16 and 64 + w*16); K/V LDS reads are
// shared between strips (half the LDS reads per MFMA, half the staging events total).
// QK: mfma(A=K-rows(perm), B=Q) -> S^T; P stays in-lane (cvt_pk) and feeds PV directly.
// PV: mfma(A=VT rows 0..143 (128 c + y + ones + zero pad), B=P) -> U^T + stats.
__global__ __launch_bounds__(256, 2) void attn_kernel(
    const unsigned short* __restrict__ xhat,
    const unsigned short* __restrict__ xhatT,
    const unsigned short* __restrict__ q2,
    const int* __restrict__ cq,
    unsigned short* __restrict__ Upart,
    float* __restrict__ lpart,
    float* __restrict__ wypart)
{
    __shared__ __align__(16) char pool[34816];   // K 16K @0, VT 18K (144 rows) @16384

    const int tid = threadIdx.x;
    const int w = tid >> 6;
    const int lane = tid & 63;
    const int g = lane >> 4;
    const int l15 = lane & 15;

    // staircase id -> (qb, chunk); expected-active cells (chunk < 4*(qb+1)) first
    int qb, chunk;
    {
        int id = blockIdx.x;                 // 0..1023 over 16 x 64 cells
        if (id < 544) {
            int q = 0, base = 0;
            while (id >= base + 4*(q + 1)) { base += 4*(q + 1); ++q; }
            qb = q; chunk = id - base;
        } else {
            int k = id - 544;
            int q = 0;
            while (k >= 64 - 4*(q + 1)) { k -= 64 - 4*(q + 1); ++q; }
            qb = q; chunk = 4*(q + 1) + k;
        }
    }

    const int cbase = chunk*KCHUNK;
    const int cqmax = cq[qb*QBS + QBS - 1];      // queries sorted ascending
    int ntiles = (cqmax - cbase + 63) >> 6;
    if (ntiles <= 0) return;                     // matches final's na predicate exactly
    if (ntiles > KCHUNK/64) ntiles = KCHUNK/64;

    const int qrow0 = qb*QBS + w*16;
    short8 qf0[4], qf1[4];
    #pragma unroll
    for (int cs = 0; cs < 4; ++cs) {
        qf0[cs] = *(const short8*)(q2 + (size_t)(qrow0 + l15)*CC + cs*32 + g*8);
        qf1[cs] = *(const short8*)(q2 + (size_t)(qrow0 + 64 + l15)*CC + cs*32 + g*8);
    }
    const int cqv0 = cq[qrow0 + l15];
    const int cqv1 = cq[qrow0 + 64 + l15];
    const int g8 = g*8;

    f32x4 accUA[9], accUB[9];
    #pragma unroll
    for (int n = 0; n < 9; ++n) { accUA[n] = (f32x4)0.f; accUB[n] = (f32x4)0.f; }

    // pre-zero VT pad rows 130..143 (read by PV sc=8, never staged)
    if (tid < 112) {
        uint4 z = {0u, 0u, 0u, 0u};
        *(uint4*)(pool + 16384 + 130*128 + tid*16) = z;
    }

    for (int kt2 = 0; kt2 < ntiles; ++kt2) {
        const int kb0 = cbase + kt2*64;
        __syncthreads();
        // stage K tile rows 0..63 (write swizzle vr(row))
        #pragma unroll
        for (int i = 0; i < 4; ++i) {
            int cid = tid + i*256;
            int row = cid >> 4, cc = cid & 15;
            int vr = (row & 3) | (((row >> 3) & 3) << 2);
            uint4 v = *(const uint4*)(xhat + (size_t)(kb0 + row)*CC + cc*8);
            *(uint4*)(pool + row*256 + ((cc << 4) ^ (vr << 4))) = v;
        }
        // stage VT rows 0..129 (128 c + y + ones)
        #pragma unroll
        for (int i = 0; i < 5; ++i) {
            int cid = tid + i*256;
            if (cid < 1040) {
                int c = cid >> 3, cc = cid & 7;
                uint4 v = *(const uint4*)(xhatT + (size_t)c*MM + kb0 + cc*8);
                *(uint4*)(pool + 16384 + c*128 + ((cc << 4) ^ ((c & 7) << 4))) = v;
            }
        }
        __syncthreads();

        const int cut0 = cqv0 - kb0;
        const int cut1 = cqv1 - kb0;
        u32 pw0[8], pw1[8];
        #pragma unroll
        for (int s = 0; s < 4; ++s) {
            // A-row a holds key kappa(s,a); for lane l15: vr(kappa) == l15
            const int krow = ((s >> 1) << 5) + ((l15 & 12) << 1) + ((s & 1) << 2) + (l15 & 3);
            f32x4 st0 = (f32x4)0.f, st1 = (f32x4)0.f;
            #pragma unroll
            for (int cs = 0; cs < 4; ++cs) {
                short8 kfr = *(const short8*)(pool + krow*256 + ((cs*64 + g*16) ^ (l15 << 4)));
                st0 = __builtin_amdgcn_mfma_f32_16x16x32_bf16(kfr, qf0[cs], st0, 0, 0, 0);
                st1 = __builtin_amdgcn_mfma_f32_16x16x32_bf16(kfr, qf1[cs], st1, 0, 0, 0);
            }
            const int kbase = ((s >> 1) << 5) + g8 + ((s & 1) << 2);
            float p00 = (kbase + 0 < cut0) ? exp2f(st0[0]) : 0.f;
            float p01 = (kbase + 1 < cut0) ? exp2f(st0[1]) : 0.f;
            float p02 = (kbase + 2 < cut0) ? exp2f(st0[2]) : 0.f;
            float p03 = (kbase + 3 < cut0) ? exp2f(st0[3]) : 0.f;
            float p10 = (kbase + 0 < cut1) ? exp2f(st1[0]) : 0.f;
            float p11 = (kbase + 1 < cut1) ? exp2f(st1[1]) : 0.f;
            float p12 = (kbase + 2 < cut1) ? exp2f(st1[2]) : 0.f;
            float p13 = (kbase + 3 < cut1) ? exp2f(st1[3]) : 0.f;
            pw0[s*2]     = cvtpk(p00, p01);
            pw0[s*2 + 1] = cvtpk(p02, p03);
            pw1[s*2]     = cvtpk(p10, p11);
            pw1[s*2 + 1] = cvtpk(p12, p13);
        }
        u32x4 a0v = {pw0[0], pw0[1], pw0[2], pw0[3]};
        u32x4 a1v = {pw0[4], pw0[5], pw0[6], pw0[7]};
        u32x4 b0v = {pw1[0], pw1[1], pw1[2], pw1[3]};
        u32x4 b1v = {pw1[4], pw1[5], pw1[6], pw1[7]};
        short8 paA0 = __builtin_bit_cast(short8, a0v);
        short8 paA1 = __builtin_bit_cast(short8, a1v);
        short8 paB0 = __builtin_bit_cast(short8, b0v);
        short8 paB1 = __builtin_bit_cast(short8, b1v);

        __builtin_amdgcn_s_setprio(1);
        #pragma unroll
        for (int sc = 0; sc < 9; ++sc) {
            const int vrow = sc*16 + l15;
            const char* Vr = pool + 16384 + vrow*128;
            const int swz = (vrow & 7) << 4;
            short8 vf0 = *(const short8*)(Vr + ((g*16) ^ swz));
            short8 vf1 = *(const short8*)(Vr + ((64 + g*16) ^ swz));
            accUA[sc] = __builtin_amdgcn_mfma_f32_16x16x32_bf16(vf0, paA0, accUA[sc], 0, 0, 0);
            accUA[sc] = __builtin_amdgcn_mfma_f32_16x16x32_bf16(vf1, paA1, accUA[sc], 0, 0, 0);
            accUB[sc] = __builtin_amdgcn_mfma_f32_16x16x32_bf16(vf0, paB0, accUB[sc], 0, 0, 0);
            accUB[sc] = __builtin_amdgcn_mfma_f32_16x16x32_bf16(vf1, paB1, accUB[sc], 0, 0, 0);
        }
        __builtin_amdgcn_s_setprio(0);
    }

    // ---- epilogue ----
    const int cell = qb*NSPLIT + chunk;
    if (g == 0) {
        wypart[cell*QBS + w*16 + l15]      = accUA[8][0];
        lpart [cell*QBS + w*16 + l15]      = accUA[8][1];
        wypart[cell*QBS + 64 + w*16 + l15] = accUB[8][0];
        lpart [cell*QBS + 64 + w*16 + l15] = accUB[8][1];
    }
    __syncthreads();                     // all waves done reading pool; reuse as bounce
    char* bounce = pool + w*4352;        // per-wave 16 q-rows x 272B
    #pragma unroll
    for (int qs = 0; qs < 2; ++qs) {
        const f32x4* acc = (qs == 0) ? accUA : accUB;
        #pragma unroll
        for (int sc = 0; sc < 8; ++sc) {
            #pragma unroll
            for (int jp = 0; jp < 2; ++jp) {
                u32 pk = cvtpk(acc[sc][2*jp], acc[sc][2*jp + 1]);
                *(u32*)(bounce + l15*272 + (sc*16 + g*4 + 2*jp)*2) = pk;
            }
        }
        asm volatile("s_waitcnt lgkmcnt(0)" ::: "memory");
        __builtin_amdgcn_sched_barrier(0);
        #pragma unroll
        for (int p = 0; p < 4; ++p) {
            int seg = p*4 + (lane & 3);
            int q = lane >> 2;
            uint4 v = *(const uint4*)(bounce + q*272 + seg*16);
            *(uint4*)((char*)Upart + (size_t)(cell*QBS + qs*64 + w*16 + q)*256 + seg*16) = v;
        }
        asm volatile("s_waitcnt lgkmcnt(0)" ::: "memory");
        __builtin_amdgcn_sched_barrier(0);
    }
}

// ---------------- fused combine + epilogue MLP ----------------------------------------
__global__ __launch_bounds__(256) void final_kernel(
    const float* __restrict__ feat, const unsigned short* __restrict__ Upart,
    const float* __restrict__ lpart, const float* __restrict__ wypart,
    const int* __restrict__ cq,
    const float* __restrict__ a, const float* __restrict__ etab,
    const float* __restrict__ msgw, const int* __restrict__ qperm,
    const float* __restrict__ uw1, const float* __restrict__ ub1,
    const float* __restrict__ uw2, const float* __restrict__ ub2,
    float* __restrict__ out)
{
    __shared__ float fl[4][128], t0[4][128], t1l[4][128];
    const int t = threadIdx.x;
    const int w = t >> 6;
    const int lane = t & 63;
    const int b = blockIdx.x*4 + w;      // sorted row
    const int qb = b >> 7;               // 128-row q-blocks
    const int cqmax = cq[qb*QBS + QBS - 1];
    int na = (cqmax + KCHUNK - 1) >> 10; // KCHUNK = 1024
    if (na > NSPLIT) na = NSPLIT;        // >= 1 since key 0 always allowed
    const int ob = qperm[b];             // original row
    const int rowin = b & (QBS - 1);
    const int j0 = lane, j1 = lane + 64;
    float f0 = feat[ob*CC + j0], f1 = feat[ob*CC + j1];
    fl[w][j0] = f0; fl[w][j1] = f1;
    float lv = 0.f, wv = 0.f;
    if (lane < na) {
        int o = (qb*NSPLIT + lane)*QBS + rowin;
        lv = lpart[o]; wv = wypart[o];
    }
    #pragma unroll
    for (int m2 = 1; m2 < 64; m2 <<= 1) {
        lv += __shfl_xor(lv, m2, 64);
        wv += __shfl_xor(wv, m2, 64);
    }
    // U sums: packed u32 loads, lane handles columns 2*lane, 2*lane+1
    float ua = 0.f, ub = 0.f;
    for (int j = 0; j < na; ++j) {
        const unsigned short* up = Upart + (size_t)((qb*NSPLIT + j)*QBS + rowin)*CC;
        u32 pk = *(const u32*)(up + 2*lane);
        ua += bf2f((unsigned short)(pk & 0xffff));
        ub += bf2f((unsigned short)(pk >> 16));
    }
    t0[w][2*lane] = ua; t0[w][2*lane + 1] = ub;
    __syncthreads();
    float linv = 1.0f / lv;
    float s1 = wv / lv;
    float acc0 = 0.f, acc1 = 0.f;
    for (int i = 0; i < 128; ++i) {
        float x = t0[w][i];
        acc0 = fmaf(x, msgw[(128 + i)*128 + j0], acc0);
        acc1 = fmaf(x, msgw[(128 + i)*128 + j1], acc1);
    }
    float mix0 = (1.f - s1)*etab[j0] + s1*etab[128 + j0];
    float mix1 = (1.f - s1)*etab[j1] + s1*etab[128 + j1];
    float hg0 = a[ob*CC + j0] + acc0*linv + mix0;
    float hg1 = a[ob*CC + j1] + acc1*linv + mix1;
    __syncthreads();
    t0[w][j0] = hg0; t0[w][j1] = hg1;
    __syncthreads();
    float h0 = ub1[j0], h1 = ub1[j1];
    for (int i = 0; i < 128; ++i) {
        float xf = fl[w][i];
        float xh = t0[w][i];
        h0 = fmaf(xf, uw1[i*128 + j0], h0);
        h1 = fmaf(xf, uw1[i*128 + j1], h1);
        h0 = fmaf(xh, uw1[(128 + i)*128 + j0], h0);
        h1 = fmaf(xh, uw1[(128 + i)*128 + j1], h1);
    }
    h0 = fmaxf(h0, 0.f); h1 = fmaxf(h1, 0.f);
    t1l[w][j0] = h0; t1l[w][j1] = h1;
    __syncthreads();
    float o0 = ub2[j0], o1 = ub2[j1];
    for (int i = 0; i < 128; ++i) {
        float x = t1l[w][i];
        o0 = fmaf(x, uw2[i*128 + j0], o0);
        o1 = fmaf(x, uw2[i*128 + j1], o1);
    }
    out[ob*CC + j0] = f0 + o0;
    out[ob*CC + j1] = f1 + o1;
}

extern "C" void kernel_launch(void* const* d_in, const int* in_sizes, int n_in,
                              void* d_out, int out_size, void* d_ws, size_t ws_size,
                              hipStream_t stream) {
    (void)in_sizes; (void)n_in; (void)out_size; (void)ws_size;
    const float* feature  = (const float*)d_in[0];
    const float* memory_x = (const float*)d_in[1];
    const int*   memory_y = (const int*)d_in[2];
    const float* seed_t   = (const float*)d_in[3];
    const float* mem_st   = (const float*)d_in[4];
    const float* key_w    = (const float*)d_in[5];
    const float* key_b    = (const float*)d_in[6];
    const float* msg_w    = (const float*)d_in[7];
    const float* msg_b    = (const float*)d_in[8];
    const float* upd_w1   = (const float*)d_in[9];
    const float* upd_b1   = (const float*)d_in[10];
    const float* upd_w2   = (const float*)d_in[11];
    const float* upd_b2   = (const float*)d_in[12];
    const float* y_emb    = (const float*)d_in[13];
    float* out = (float*)d_out;

    // ---- bump-allocated workspace (256B aligned) ----
    char* ws = (char*)d_ws;
    size_t off = 0;
    auto A = [&](size_t bytes) -> char* {
        char* p = ws + off;
        off += (bytes + 255) & ~(size_t)255;
        return p;
    };
    unsigned short* xhat  = (unsigned short*)A((size_t)MM*CC*2);         // 16 MB
    unsigned short* xhatT = (unsigned short*)A((size_t)MM*130*2);        // 17 MB
    unsigned short* q2    = (unsigned short*)A((size_t)BQ*CC*2);         // 512 KB
    float* a      = (float*)A((size_t)BQ*CC*4);                          // 1 MB
    float* etab   = (float*)A(2*CC*4);
    float* lpart  = (float*)A((size_t)NQB2*NSPLIT*QBS*4);                // 512 KB
    float* wypart = (float*)A((size_t)NQB2*NSPLIT*QBS*4);                // 512 KB
    int*   dperm  = (int*)A((size_t)MM*4);                               // 256 KB
    float* mst_s  = (float*)A((size_t)MM*4);                             // 256 KB
    unsigned int* btot  = (unsigned int*)A(NBUCKET*4);
    unsigned int* gbase = (unsigned int*)A(NBUCKET*4);
    int*   qperm  = (int*)A(BQ*4);
    int*   qrank  = (int*)A(BQ*4);
    float* seed_s = (float*)A(BQ*4);
    int*   cqbuf  = (int*)A(BQ*4);
    unsigned short* Upart = (unsigned short*)A((size_t)NQB2*NSPLIT*QBS*CC*2); // 33.5 MB
    // histT aliases Upart: consumed by sort_scatter before attn writes Upart.
    unsigned int* histT = (unsigned int*)Upart;                          // 1 MB

    qrank_kernel<<<BQ/8, 256, 0, stream>>>(seed_t, qperm, qrank, seed_s);
    sort_hist_kernel<<<MM/256, 256, 0, stream>>>(mem_st, histT);
    sort_scanA_kernel<<<NBUCKET, 64, 0, stream>>>(histT, btot);
    sort_scanB_kernel<<<1, 1024, 0, stream>>>(btot, gbase);
    sort_scatter_kernel<<<MM/256, 256, 0, stream>>>(mem_st, histT, gbase, dperm, mst_s);
    sortfix_kernel<<<NBUCKET, 64, 0, stream>>>(mst_s, dperm, gbase, btot);
    cq_kernel<<<BQ/256, 256, 0, stream>>>(seed_s, mst_s, gbase, btot, cqbuf);
    mem_norm_kernel<<<MM/128, 256, 0, stream>>>(memory_x, dperm, memory_y, xhat, xhatT);
    query_prep_kernel<<<BQ/4 + 1, 256, 0, stream>>>(feature, key_w, key_b, msg_w, msg_b,
                                                    y_emb, qrank, q2, a, etab);
    attn_kernel<<<NQB2*NSPLIT, 256, 0, stream>>>(xhat, xhatT, q2, cqbuf,
                                                 Upart, lpart, wypart);
    final_kernel<<<BQ/4, 256, 0, stream>>>(feature, Upart, lpart, wypart, cqbuf,
                                           a, etab, msg_w, qperm,
                                           upd_w1, upd_b1, upd_w2, upd_b2, out);
}

// Round 12
// 233.160 us; speedup vs baseline: 1.1082x; 1.1082x over previous
//
#include <hip/hip_runtime.h>

#define BQ 2048
#define MM 65536
#define CC 128
#define QBS 64
#define NQB 32
#define NSPLIT 64
#define KCHUNK (MM/NSPLIT)      // 1024
#define NBUCKET 1024
#define NACT 1056               // sum of 2*(qb+1), qb=0..31

typedef short short8 __attribute__((ext_vector_type(8)));
typedef float f32x4 __attribute__((ext_vector_type(4)));
typedef unsigned int u32x4 __attribute__((ext_vector_type(4)));
typedef unsigned int u32;

__device__ __forceinline__ unsigned short f2bf(float x) {
    unsigned int u = __builtin_bit_cast(unsigned int, x);
    u = (u + 0x7FFFu + ((u >> 16) & 1u)) >> 16;
    return (unsigned short)u;
}
__device__ __forceinline__ float bf2f(unsigned short u) {
    return __builtin_bit_cast(float, (unsigned int)u << 16);
}
__device__ __forceinline__ int bucket_of(float v) {
    return (int)fminf(fmaxf(v * 1024.0f, 0.0f), 1023.0f);
}
__device__ __forceinline__ u32 cvtpk(float lo, float hi) {
    u32 r;
    asm("v_cvt_pk_bf16_f32 %0, %1, %2" : "=v"(r) : "v"(lo), "v"(hi));
    return r;
}

// ---------------- exact query rank by seed_time (parallel, deterministic) -------------
__global__ __launch_bounds__(256) void qrank_kernel(
    const float* __restrict__ seed, int* __restrict__ qperm,
    int* __restrict__ qrank, float* __restrict__ seed_s)
{
    int t = threadIdx.x;
    int q = blockIdx.x*8 + (t >> 5);
    int l32 = t & 31;
    float v = seed[q];
    int r = 0;
    for (int seg = 0; seg < 64; ++seg) {
        int j = seg*32 + l32;
        float u = seed[j];
        r += (u < v) || (u == v && j < q);
    }
    #pragma unroll
    for (int m2 = 1; m2 < 32; m2 <<= 1) r += __shfl_xor(r, m2, 32);
    if (l32 == 0) { qperm[r] = q; qrank[q] = r; seed_s[r] = v; }
}

// ---------------- counting sort of memory keys by mst ---------------------------------
__global__ __launch_bounds__(256) void sort_hist_kernel(
    const float* __restrict__ mst, unsigned int* __restrict__ histT)
{
    __shared__ unsigned int h[NBUCKET];
    int t = threadIdx.x, b = blockIdx.x;
    #pragma unroll
    for (int j = t; j < NBUCKET; j += 256) h[j] = 0;
    __syncthreads();
    int bin = bucket_of(mst[b*256 + t]);
    atomicAdd(&h[bin], 1u);
    __syncthreads();
    #pragma unroll
    for (int j = t; j < NBUCKET; j += 256) histT[(size_t)j*256 + b] = h[j];
}

__global__ __launch_bounds__(64) void sort_scanA_kernel(
    unsigned int* __restrict__ histT, unsigned int* __restrict__ btot)
{
    int j = blockIdx.x;
    int t = threadIdx.x;
    uint4 v = *(uint4*)(histT + (size_t)j*256 + t*4);
    unsigned int s0 = v.x, s1 = v.y, s2 = v.z, s3 = v.w;
    unsigned int tsum = s0 + s1 + s2 + s3;
    unsigned int inc = tsum;
    #pragma unroll
    for (int off = 1; off < 64; off <<= 1) {
        unsigned int n = __shfl_up(inc, off, 64);
        if (t >= off) inc += n;
    }
    unsigned int ex = inc - tsum;
    uint4 o;
    o.x = ex; o.y = ex + s0; o.z = ex + s0 + s1; o.w = ex + s0 + s1 + s2;
    *(uint4*)(histT + (size_t)j*256 + t*4) = o;
    if (t == 63) btot[j] = inc;
}

__global__ __launch_bounds__(1024) void sort_scanB_kernel(
    const unsigned int* __restrict__ btot, unsigned int* __restrict__ gbase)
{
    __shared__ unsigned int sc[NBUCKET];
    int j = threadIdx.x;
    unsigned int tot = btot[j];
    sc[j] = tot;
    __syncthreads();
    for (int off = 1; off < NBUCKET; off <<= 1) {
        unsigned int y = (j >= off) ? sc[j - off] : 0u;
        __syncthreads();
        sc[j] += y;
        __syncthreads();
    }
    gbase[j] = sc[j] - tot;
}

__global__ __launch_bounds__(256) void sort_scatter_kernel(
    const float* __restrict__ mst, const unsigned int* __restrict__ histT,
    const unsigned int* __restrict__ gbase,
    int* __restrict__ dperm, float* __restrict__ mst_s)
{
    __shared__ int bins[256];
    int t = threadIdx.x, b = blockIdx.x;
    int i = b*256 + t;
    float v = mst[i];
    int bin = bucket_of(v);
    bins[t] = bin;
    __syncthreads();
    int pos = 0;
    for (int j = 0; j < t; ++j) pos += (bins[j] == bin);
    unsigned int dest = gbase[bin] + histT[(size_t)bin*256 + b] + pos;
    dperm[dest] = i;
    mst_s[dest] = v;
}

// ---------------- exact intra-bucket sort (value, orig idx) ---------------------------
__global__ __launch_bounds__(64) void sortfix_kernel(
    float* __restrict__ mst_s, int* __restrict__ dperm,
    const unsigned int* __restrict__ gbase, const unsigned int* __restrict__ btot)
{
    __shared__ float vals[512];
    __shared__ int idxs[512];
    int b = blockIdx.x;
    int base = (int)gbase[b];
    int n = (int)btot[b];
    if (n > 512) n = 512;
    if (n <= 1) return;
    int t = threadIdx.x;
    for (int i = t; i < n; i += 64) { vals[i] = mst_s[base + i]; idxs[i] = dperm[base + i]; }
    __syncthreads();
    for (int i = t; i < n; i += 64) {
        float v = vals[i]; int d = idxs[i];
        int rank = 0;
        for (int j = 0; j < n; ++j) {
            float vj = vals[j];
            rank += (vj < v) || (vj == v && idxs[j] < d);
        }
        mst_s[base + rank] = v;
        dperm[base + rank] = d;
    }
}

// ---------------- exact cut position per sorted query row -----------------------------
__global__ __launch_bounds__(256) void cq_kernel(
    const float* __restrict__ seed_s, const float* __restrict__ mst_s,
    const unsigned int* __restrict__ gbase, const unsigned int* __restrict__ btot,
    int* __restrict__ cq)
{
    int r = blockIdx.x*256 + threadIdx.x;
    float s = seed_s[r];
    int b = bucket_of(s);
    int base = (int)gbase[b];
    int n = (int)btot[b];
    int cnt = 0;
    for (int i = 0; i < n; ++i) cnt += (mst_s[base + i] <= s) ? 1 : 0;
    cq[r] = base + cnt;
}

// ---------------- memory l2norm (gathered) -> FK/FV fragment-major + y_s --------------
// FK[tile][s][cs][lane(64)x16B]: lane holds xhat[kappa(s,lane&15)][cs*32+(lane>>4)*8 ..+7]
//   kappa(s,a) = (s>>1)*32 + (a>>2)*8 + (s&1)*4 + (a&3)
// FV[tile][sc][kk][lane x16B]: lane holds xhatT[sc*16+(lane&15)][kk*32+(lane>>4)*8 ..+7]
__global__ __launch_bounds__(256) void mem_norm_kernel(
    const float* __restrict__ mx, const int* __restrict__ dperm,
    const int* __restrict__ memy,
    char* __restrict__ FK, char* __restrict__ FV, float* __restrict__ y_s)
{
    __shared__ __align__(16) unsigned short tile[128*132];  // bf16, stride 132
    __shared__ float rs[128];
    __shared__ float invn[128];
    __shared__ int operm[128];
    const int t = threadIdx.x;
    const int kb0 = blockIdx.x * 128;
    const int gt0 = blockIdx.x * 2;          // two 64-key tiles per block

    if (t < 128) operm[t] = dperm[kb0 + t];
    __syncthreads();
    if (t < 128) y_s[kb0 + t] = (float)memy[operm[t]];

    float4 vals[16];
    #pragma unroll
    for (int i = 0; i < 16; ++i) {
        int f4 = t + 256*i;
        int row = f4 >> 5, col4 = f4 & 31;
        float4 v = *(const float4*)(mx + (size_t)operm[row]*CC + col4*4);
        vals[i] = v;
        float s = v.x*v.x + v.y*v.y + v.z*v.z + v.w*v.w;
        #pragma unroll
        for (int m2 = 1; m2 < 32; m2 <<= 1) s += __shfl_xor(s, m2, 64);
        if ((t & 31) == 0) rs[row] = s;
    }
    __syncthreads();
    if (t < 128) invn[t] = 1.0f / fmaxf(sqrtf(rs[t]), 1e-12f);
    __syncthreads();
    #pragma unroll
    for (int i = 0; i < 16; ++i) {
        int f4 = t + 256*i;
        int row = f4 >> 5, col4 = f4 & 31;
        float sc = invn[row];
        float4 v = vals[i];
        ushort4 o;
        o.x = f2bf(v.x*sc); o.y = f2bf(v.y*sc); o.z = f2bf(v.z*sc); o.w = f2bf(v.w*sc);
        *(ushort4*)&tile[row*132 + col4*4] = o;
    }
    __syncthreads();
    // FK: 2048 16B units, coalesced 1KB runs
    #pragma unroll
    for (int i = 0; i < 8; ++i) {
        int u = t + 256*i;
        int tl = u >> 10;
        int s  = (u >> 8) & 3;
        int cs = (u >> 6) & 3;
        int ln = u & 63;
        int a = ln & 15, grp = ln >> 4;
        int row = tl*64 + ((s >> 1) << 5) + ((a & 12) << 1) + ((s & 1) << 2) + (a & 3);
        int col = cs*32 + grp*8;
        ushort4 p0 = *(ushort4*)&tile[row*132 + col];
        ushort4 p1 = *(ushort4*)&tile[row*132 + col + 4];
        char* dst = FK + ((size_t)(gt0 + tl)*16 + s*4 + cs)*1024 + ln*16;
        *(ushort4*)dst = p0;
        *(ushort4*)(dst + 8) = p1;
    }
    // FV: 2048 16B units (8 sc x 2 kk x 64 lanes x 2 tiles), transpose gather from LDS
    #pragma unroll
    for (int i = 0; i < 8; ++i) {
        int u = t + 256*i;
        int tl = u >> 10;
        int v2 = u & 1023;
        int sc = v2 >> 7;
        int rest = v2 & 127;
        int kk = rest >> 6;
        int ln = rest & 63;
        int c = sc*16 + (ln & 15);
        int key0 = tl*64 + kk*32 + (ln >> 4)*8;
        u32 w0 = (u32)tile[(key0+0)*132 + c] | ((u32)tile[(key0+1)*132 + c] << 16);
        u32 w1 = (u32)tile[(key0+2)*132 + c] | ((u32)tile[(key0+3)*132 + c] << 16);
        u32 w2 = (u32)tile[(key0+4)*132 + c] | ((u32)tile[(key0+5)*132 + c] << 16);
        u32 w3 = (u32)tile[(key0+6)*132 + c] | ((u32)tile[(key0+7)*132 + c] << 16);
        uint4 o; o.x = w0; o.y = w1; o.z = w2; o.w = w3;
        *(uint4*)(FV + ((size_t)(gt0 + tl)*16 + sc*2 + kk)*1024 + ln*16) = o;
    }
}

// ---------------- query prep (+ etab fold): q2 = (l2norm(f)@Kw + kb)@Kw^T * log2e -----
__global__ __launch_bounds__(256) void query_prep_kernel(
    const float* __restrict__ feat, const float* __restrict__ keyw,
    const float* __restrict__ keyb, const float* __restrict__ msgw,
    const float* __restrict__ msgb, const float* __restrict__ yemb,
    const int* __restrict__ qrank,
    unsigned short* __restrict__ q2, float* __restrict__ a,
    float* __restrict__ etab)
{
    __shared__ float fl[4][128], t1[4][128];
    const int t = threadIdx.x;
    if (blockIdx.x == BQ/4) {
        if (t < 128) {
            float acc0 = msgb[t], acc1 = msgb[t];
            for (int c2 = 0; c2 < 128; ++c2) {
                float w3 = msgw[(256 + c2)*128 + t];
                acc0 = fmaf(yemb[c2], w3, acc0);
                acc1 = fmaf(yemb[128 + c2], w3, acc1);
            }
            etab[t] = acc0;
            etab[128 + t] = acc1;
        }
        return;
    }
    const int w = t >> 6;
    const int lane = t & 63;
    const int b = blockIdx.x*4 + w;
    const int j0 = lane, j1 = lane + 64;
    float f0 = feat[b*CC + j0], f1 = feat[b*CC + j1];
    fl[w][j0] = f0; fl[w][j1] = f1;
    float s = f0*f0 + f1*f1;
    #pragma unroll
    for (int m2 = 1; m2 < 64; m2 <<= 1) s += __shfl_xor(s, m2, 64);
    float invn = 1.0f / fmaxf(sqrtf(s), 1e-12f);
    __syncthreads();
    float g0 = 0.f, g1 = 0.f, a0 = 0.f, a1 = 0.f;
    for (int i = 0; i < 128; ++i) {
        float x = fl[w][i];
        g0 = fmaf(x, keyw[i*128 + j0], g0);
        g1 = fmaf(x, keyw[i*128 + j1], g1);
        a0 = fmaf(x, msgw[i*128 + j0], a0);
        a1 = fmaf(x, msgw[i*128 + j1], a1);
    }
    t1[w][j0] = g0*invn + keyb[j0];
    t1[w][j1] = g1*invn + keyb[j1];
    a[b*CC + j0] = a0;
    a[b*CC + j1] = a1;
    __syncthreads();
    float q0 = 0.f, q1 = 0.f;
    for (int c2 = 0; c2 < 128; ++c2) {
        float u = t1[w][c2];
        q0 = fmaf(u, keyw[j0*128 + c2], q0);
        q1 = fmaf(u, keyw[j1*128 + c2], q1);
    }
    const float LOG2E = 1.4426950408889634f;
    int rb = qrank[b];
    q2[rb*CC + j0] = f2bf(q0 * LOG2E);
    q2[rb*CC + j1] = f2bf(q1 * LOG2E);
}

// ---------------- flash attention: barrier-free fragment streaming --------------------
// Operands pre-tiled in MFMA-fragment order -> every load is one coalesced 1KB
// global_load_dwordx4. No staging LDS, no __syncthreads: waves free-run; latency
// hidden by ~16 waves/CU. QK: mfma(A=FK-frag, B=Q) -> S^T (q=lane&15); P stays in-lane
// (cvt_pk) and feeds PV: mfma(A=FV-frag, B=P) -> U^T. Stats: f32 accl/accw + shfl.
__global__ __launch_bounds__(256, 4) void attn_kernel(
    const char* __restrict__ FK,
    const char* __restrict__ FV,
    const unsigned short* __restrict__ q2,
    const int* __restrict__ cq,
    const float* __restrict__ y_s,
    unsigned short* __restrict__ Upart,
    float* __restrict__ lpart,
    float* __restrict__ wypart)
{
    __shared__ __align__(16) char bounce[4][4352];   // per-wave transpose bounce

    const int tid = threadIdx.x;
    const int w = tid >> 6;
    const int lane = tid & 63;
    const int g = lane >> 4;
    const int l15 = lane & 15;

    // staircase id -> (qb, chunk): expected-active cells (chunk < 2*(qb+1)) first
    int qb, chunk;
    {
        int id = blockIdx.x;                 // 0..2047 over 32 x 64 cells
        if (id < NACT) {
            int q = 0, base = 0;
            while (id >= base + 2*(q + 1)) { base += 2*(q + 1); ++q; }
            qb = q; chunk = id - base;
        } else {
            int k = id - NACT;
            int q = 0;
            while (k >= 64 - 2*(q + 1)) { k -= 64 - 2*(q + 1); ++q; }
            qb = q; chunk = 2*(q + 1) + k;
        }
    }

    const int cbase = chunk*KCHUNK;
    const int cqmax = cq[qb*QBS + QBS - 1];
    int ntiles = (cqmax - cbase + 63) >> 6;
    if (ntiles <= 0) return;                 // matches final's na predicate exactly
    if (ntiles > KCHUNK/64) ntiles = KCHUNK/64;

    const int qrow0 = qb*QBS + w*16;
    short8 qf[4];
    #pragma unroll
    for (int cs = 0; cs < 4; ++cs)
        qf[cs] = *(const short8*)(q2 + (size_t)(qrow0 + l15)*CC + cs*32 + g*8);
    const int cqv = cq[qrow0 + l15];
    const int g8 = g*8;

    f32x4 accU[8];
    #pragma unroll
    for (int n = 0; n < 8; ++n) accU[n] = (f32x4)0.f;
    float accl = 0.f, accw = 0.f;

    const int gt00 = cbase >> 6;
    for (int kt2 = 0; kt2 < ntiles; ++kt2) {
        const int kb0 = cbase + kt2*64;
        const char* Kf = FK + (size_t)(gt00 + kt2)*16384;
        const char* Vf = FV + (size_t)(gt00 + kt2)*16384;
        const int cut = cqv - kb0;

        u32 pw[8];
        #pragma unroll
        for (int s = 0; s < 4; ++s) {
            f32x4 st = (f32x4)0.f;
            #pragma unroll
            for (int cs = 0; cs < 4; ++cs) {
                short8 kfr = *(const short8*)(Kf + ((s*4 + cs)*64 + lane)*16);
                st = __builtin_amdgcn_mfma_f32_16x16x32_bf16(kfr, qf[cs], st, 0, 0, 0);
            }
            const int kbase = ((s >> 1) << 5) + g8 + ((s & 1) << 2);
            float4 y4 = *(const float4*)(y_s + kb0 + kbase);
            float p0 = (kbase + 0 < cut) ? exp2f(st[0]) : 0.f;
            float p1 = (kbase + 1 < cut) ? exp2f(st[1]) : 0.f;
            float p2 = (kbase + 2 < cut) ? exp2f(st[2]) : 0.f;
            float p3 = (kbase + 3 < cut) ? exp2f(st[3]) : 0.f;
            accl += p0 + p1 + p2 + p3;
            accw = fmaf(p0, y4.x, fmaf(p1, y4.y, fmaf(p2, y4.z, fmaf(p3, y4.w, accw))));
            pw[s*2]     = cvtpk(p0, p1);
            pw[s*2 + 1] = cvtpk(p2, p3);
        }
        u32x4 t0v = {pw[0], pw[1], pw[2], pw[3]};
        u32x4 t1v = {pw[4], pw[5], pw[6], pw[7]};
        short8 pa0 = __builtin_bit_cast(short8, t0v);
        short8 pa1 = __builtin_bit_cast(short8, t1v);

        #pragma unroll
        for (int sc = 0; sc < 8; ++sc) {
            short8 vf0 = *(const short8*)(Vf + ((sc*2 + 0)*64 + lane)*16);
            short8 vf1 = *(const short8*)(Vf + ((sc*2 + 1)*64 + lane)*16);
            accU[sc] = __builtin_amdgcn_mfma_f32_16x16x32_bf16(vf0, pa0, accU[sc], 0, 0, 0);
            accU[sc] = __builtin_amdgcn_mfma_f32_16x16x32_bf16(vf1, pa1, accU[sc], 0, 0, 0);
        }
    }

    // ---- epilogue (per-wave, no block barriers) ----
    const int cell = qb*NSPLIT + chunk;
    accl += __shfl_xor(accl, 16, 64); accl += __shfl_xor(accl, 32, 64);
    accw += __shfl_xor(accw, 16, 64); accw += __shfl_xor(accw, 32, 64);
    if (lane < 16) {
        lpart [cell*QBS + w*16 + lane] = accl;
        wypart[cell*QBS + w*16 + lane] = accw;
    }
    char* bw = bounce[w];
    #pragma unroll
    for (int sc = 0; sc < 8; ++sc) {
        #pragma unroll
        for (int jp = 0; jp < 2; ++jp) {
            u32 pk = cvtpk(accU[sc][2*jp], accU[sc][2*jp + 1]);
            *(u32*)(bw + l15*272 + (sc*16 + g*4 + 2*jp)*2) = pk;
        }
    }
    asm volatile("s_waitcnt lgkmcnt(0)" ::: "memory");
    __builtin_amdgcn_sched_barrier(0);
    #pragma unroll
    for (int p = 0; p < 4; ++p) {
        int seg = p*4 + (lane & 3);
        int q = lane >> 2;
        uint4 v = *(const uint4*)(bw + q*272 + seg*16);
        *(uint4*)((char*)Upart + (size_t)(cell*QBS + w*16 + q)*256 + seg*16) = v;
    }
}

// ---------------- fused combine + epilogue MLP ----------------------------------------
__global__ __launch_bounds__(256) void final_kernel(
    const float* __restrict__ feat, const unsigned short* __restrict__ Upart,
    const float* __restrict__ lpart, const float* __restrict__ wypart,
    const int* __restrict__ cq,
    const float* __restrict__ a, const float* __restrict__ etab,
    const float* __restrict__ msgw, const int* __restrict__ qperm,
    const float* __restrict__ uw1, const float* __restrict__ ub1,
    const float* __restrict__ uw2, const float* __restrict__ ub2,
    float* __restrict__ out)
{
    __shared__ float fl[4][128], t0[4][128], t1l[4][128];
    const int t = threadIdx.x;
    const int w = t >> 6;
    const int lane = t & 63;
    const int b = blockIdx.x*4 + w;      // sorted row
    const int qb = b >> 6;
    const int cqmax = cq[qb*QBS + QBS - 1];
    int na = (cqmax + KCHUNK - 1) >> 10; // KCHUNK = 1024
    if (na > NSPLIT) na = NSPLIT;        // >= 1 since key 0 always allowed
    const int ob = qperm[b];             // original row
    const int rowin = b & (QBS - 1);
    const int j0 = lane, j1 = lane + 64;
    float f0 = feat[ob*CC + j0], f1 = feat[ob*CC + j1];
    fl[w][j0] = f0; fl[w][j1] = f1;
    float lv = 0.f, wv = 0.f;
    if (lane < na) {
        int o = (qb*NSPLIT + lane)*QBS + rowin;
        lv = lpart[o]; wv = wypart[o];
    }
    #pragma unroll
    for (int m2 = 1; m2 < 64; m2 <<= 1) {
        lv += __shfl_xor(lv, m2, 64);
        wv += __shfl_xor(wv, m2, 64);
    }
    float ua = 0.f, ub = 0.f;
    for (int j = 0; j < na; ++j) {
        const unsigned short* up = Upart + (size_t)((qb*NSPLIT + j)*QBS + rowin)*CC;
        u32 pk = *(const u32*)(up + 2*lane);
        ua += bf2f((unsigned short)(pk & 0xffff));
        ub += bf2f((unsigned short)(pk >> 16));
    }
    t0[w][2*lane] = ua; t0[w][2*lane + 1] = ub;
    __syncthreads();
    float linv = 1.0f / lv;
    float s1 = wv / lv;
    float acc0 = 0.f, acc1 = 0.f;
    for (int i = 0; i < 128; ++i) {
        float x = t0[w][i];
        acc0 = fmaf(x, msgw[(128 + i)*128 + j0], acc0);
        acc1 = fmaf(x, msgw[(128 + i)*128 + j1], acc1);
    }
    float mix0 = (1.f - s1)*etab[j0] + s1*etab[128 + j0];
    float mix1 = (1.f - s1)*etab[j1] + s1*etab[128 + j1];
    float hg0 = a[ob*CC + j0] + acc0*linv + mix0;
    float hg1 = a[ob*CC + j1] + acc1*linv + mix1;
    __syncthreads();
    t0[w][j0] = hg0; t0[w][j1] = hg1;
    __syncthreads();
    float h0 = ub1[j0], h1 = ub1[j1];
    for (int i = 0; i < 128; ++i) {
        float xf = fl[w][i];
        float xh = t0[w][i];
        h0 = fmaf(xf, uw1[i*128 + j0], h0);
        h1 = fmaf(xf, uw1[i*128 + j1], h1);
        h0 = fmaf(xh, uw1[(128 + i)*128 + j0], h0);
        h1 = fmaf(xh, uw1[(128 + i)*128 + j1], h1);
    }
    h0 = fmaxf(h0, 0.f); h1 = fmaxf(h1, 0.f);
    t1l[w][j0] = h0; t1l[w][j1] = h1;
    __syncthreads();
    float o0 = ub2[j0], o1 = ub2[j1];
    for (int i = 0; i < 128; ++i) {
        float x = t1l[w][i];
        o0 = fmaf(x, uw2[i*128 + j0], o0);
        o1 = fmaf(x, uw2[i*128 + j1], o1);
    }
    out[ob*CC + j0] = f0 + o0;
    out[ob*CC + j1] = f1 + o1;
}

extern "C" void kernel_launch(void* const* d_in, const int* in_sizes, int n_in,
                              void* d_out, int out_size, void* d_ws, size_t ws_size,
                              hipStream_t stream) {
    (void)in_sizes; (void)n_in; (void)out_size; (void)ws_size;
    const float* feature  = (const float*)d_in[0];
    const float* memory_x = (const float*)d_in[1];
    const int*   memory_y = (const int*)d_in[2];
    const float* seed_t   = (const float*)d_in[3];
    const float* mem_st   = (const float*)d_in[4];
    const float* key_w    = (const float*)d_in[5];
    const float* key_b    = (const float*)d_in[6];
    const float* msg_w    = (const float*)d_in[7];
    const float* msg_b    = (const float*)d_in[8];
    const float* upd_w1   = (const float*)d_in[9];
    const float* upd_b1   = (const float*)d_in[10];
    const float* upd_w2   = (const float*)d_in[11];
    const float* upd_b2   = (const float*)d_in[12];
    const float* y_emb    = (const float*)d_in[13];
    float* out = (float*)d_out;

    // ---- bump-allocated workspace (256B aligned) ----
    char* ws = (char*)d_ws;
    size_t off = 0;
    auto A = [&](size_t bytes) -> char* {
        char* p = ws + off;
        off += (bytes + 255) & ~(size_t)255;
        return p;
    };
    char* FK = A((size_t)(MM/64)*16*1024);                               // 16.78 MB
    char* FV = A((size_t)(MM/64)*16*1024);                               // 16.78 MB
    unsigned short* q2    = (unsigned short*)A((size_t)BQ*CC*2);         // 512 KB
    float* a      = (float*)A((size_t)BQ*CC*4);                          // 1 MB
    float* etab   = (float*)A(2*CC*4);
    float* lpart  = (float*)A((size_t)NQB*NSPLIT*QBS*4);                 // 512 KB
    float* wypart = (float*)A((size_t)NQB*NSPLIT*QBS*4);                 // 512 KB
    int*   dperm  = (int*)A((size_t)MM*4);                               // 256 KB
    float* mst_s  = (float*)A((size_t)MM*4);                             // 256 KB
    float* y_s    = (float*)A((size_t)MM*4);                             // 256 KB
    unsigned int* btot  = (unsigned int*)A(NBUCKET*4);
    unsigned int* gbase = (unsigned int*)A(NBUCKET*4);
    int*   qperm  = (int*)A(BQ*4);
    int*   qrank  = (int*)A(BQ*4);
    float* seed_s = (float*)A(BQ*4);
    int*   cqbuf  = (int*)A(BQ*4);
    unsigned short* Upart = (unsigned short*)A((size_t)NQB*NSPLIT*QBS*CC*2); // 33.5 MB
    // histT aliases Upart: consumed by sort_scatter before attn writes Upart.
    unsigned int* histT = (unsigned int*)Upart;                          // 1 MB

    qrank_kernel<<<BQ/8, 256, 0, stream>>>(seed_t, qperm, qrank, seed_s);
    sort_hist_kernel<<<MM/256, 256, 0, stream>>>(mem_st, histT);
    sort_scanA_kernel<<<NBUCKET, 64, 0, stream>>>(histT, btot);
    sort_scanB_kernel<<<1, 1024, 0, stream>>>(btot, gbase);
    sort_scatter_kernel<<<MM/256, 256, 0, stream>>>(mem_st, histT, gbase, dperm, mst_s);
    sortfix_kernel<<<NBUCKET, 64, 0, stream>>>(mst_s, dperm, gbase, btot);
    cq_kernel<<<BQ/256, 256, 0, stream>>>(seed_s, mst_s, gbase, btot, cqbuf);
    mem_norm_kernel<<<MM/128, 256, 0, stream>>>(memory_x, dperm, memory_y, FK, FV, y_s);
    query_prep_kernel<<<BQ/4 + 1, 256, 0, stream>>>(feature, key_w, key_b, msg_w, msg_b,
                                                    y_emb, qrank, q2, a, etab);
    attn_kernel<<<NQB*NSPLIT, 256, 0, stream>>>(FK, FV, q2, cqbuf, y_s,
                                                Upart, lpart, wypart);
    final_kernel<<<BQ/4, 256, 0, stream>>>(feature, Upart, lpart, wypart, cqbuf,
                                           a, etab, msg_w, qperm,
                                           upd_w1, upd_b1, upd_w2, upd_b2, out);
}

// Round 14
// 207.458 us; speedup vs baseline: 1.2455x; 1.1239x over previous
//
#include <hip/hip_runtime.h>

#define BQ 2048
#define MM 65536
#define CC 128
#define QBS 64
#define NQB 32
#define NSPLIT 64
#define KCHUNK (MM/NSPLIT)      // 1024
#define NBUCKET 1024
#define NACT 1056               // sum of 2*(qb+1), qb=0..31

typedef short short8 __attribute__((ext_vector_type(8)));
typedef float f32x4 __attribute__((ext_vector_type(4)));
typedef unsigned int u32x4 __attribute__((ext_vector_type(4)));
typedef unsigned int u32;

__device__ __forceinline__ unsigned short f2bf(float x) {
    unsigned int u = __builtin_bit_cast(unsigned int, x);
    u = (u + 0x7FFFu + ((u >> 16) & 1u)) >> 16;
    return (unsigned short)u;
}
__device__ __forceinline__ float bf2f(unsigned short u) {
    return __builtin_bit_cast(float, (unsigned int)u << 16);
}
__device__ __forceinline__ int bucket_of(float v) {
    return (int)fminf(fmaxf(v * 1024.0f, 0.0f), 1023.0f);
}
__device__ __forceinline__ u32 cvtpk(float lo, float hi) {
    u32 r;
    asm("v_cvt_pk_bf16_f32 %0, %1, %2" : "=v"(r) : "v"(lo), "v"(hi));
    return r;
}

// ---------------- K_A: qrank (blocks 0..255)  ||  hist (blocks 256..511) -------------
__global__ __launch_bounds__(256) void ka_kernel(
    const float* __restrict__ seed, const float* __restrict__ mst,
    int* __restrict__ qperm, int* __restrict__ qrank, float* __restrict__ seed_s,
    unsigned int* __restrict__ histT)
{
    __shared__ unsigned int h[NBUCKET];
    int t = threadIdx.x;
    if (blockIdx.x < 256) {
        int q = blockIdx.x*8 + (t >> 5);
        int l32 = t & 31;
        float v = seed[q];
        int r = 0;
        for (int seg = 0; seg < 64; ++seg) {
            int j = seg*32 + l32;
            float u = seed[j];
            r += (u < v) || (u == v && j < q);
        }
        #pragma unroll
        for (int m2 = 1; m2 < 32; m2 <<= 1) r += __shfl_xor(r, m2, 32);
        if (l32 == 0) { qperm[r] = q; qrank[q] = r; seed_s[r] = v; }
    } else {
        int b = blockIdx.x - 256;
        #pragma unroll
        for (int j = t; j < NBUCKET; j += 256) h[j] = 0;
        __syncthreads();
        int bin = bucket_of(mst[b*256 + t]);
        atomicAdd(&h[bin], 1u);
        __syncthreads();
        #pragma unroll
        for (int j = t; j < NBUCKET; j += 256) histT[(size_t)j*256 + b] = h[j];
    }
}

__global__ __launch_bounds__(64) void sort_scanA_kernel(
    unsigned int* __restrict__ histT, unsigned int* __restrict__ btot)
{
    int j = blockIdx.x;
    int t = threadIdx.x;
    uint4 v = *(uint4*)(histT + (size_t)j*256 + t*4);
    unsigned int s0 = v.x, s1 = v.y, s2 = v.z, s3 = v.w;
    unsigned int tsum = s0 + s1 + s2 + s3;
    unsigned int inc = tsum;
    #pragma unroll
    for (int off = 1; off < 64; off <<= 1) {
        unsigned int n = __shfl_up(inc, off, 64);
        if (t >= off) inc += n;
    }
    unsigned int ex = inc - tsum;
    uint4 o;
    o.x = ex; o.y = ex + s0; o.z = ex + s0 + s1; o.w = ex + s0 + s1 + s2;
    *(uint4*)(histT + (size_t)j*256 + t*4) = o;
    if (t == 63) btot[j] = inc;
}

__global__ __launch_bounds__(1024) void sort_scanB_kernel(
    const unsigned int* __restrict__ btot, unsigned int* __restrict__ gbase)
{
    __shared__ unsigned int sc[NBUCKET];
    int j = threadIdx.x;
    unsigned int tot = btot[j];
    sc[j] = tot;
    __syncthreads();
    for (int off = 1; off < NBUCKET; off <<= 1) {
        unsigned int y = (j >= off) ? sc[j - off] : 0u;
        __syncthreads();
        sc[j] += y;
        __syncthreads();
    }
    gbase[j] = sc[j] - tot;
}

__global__ __launch_bounds__(256) void sort_scatter_kernel(
    const float* __restrict__ mst, const unsigned int* __restrict__ histT,
    const unsigned int* __restrict__ gbase,
    int* __restrict__ dperm, float* __restrict__ mst_s)
{
    __shared__ int bins[256];
    int t = threadIdx.x, b = blockIdx.x;
    int i = b*256 + t;
    float v = mst[i];
    int bin = bucket_of(v);
    bins[t] = bin;
    __syncthreads();
    int pos = 0;
    for (int j = 0; j < t; ++j) pos += (bins[j] == bin);
    unsigned int dest = gbase[bin] + histT[(size_t)bin*256 + b] + pos;
    dperm[dest] = i;
    mst_s[dest] = v;
}

// ---------------- exact intra-bucket sort (value, orig idx) ---------------------------
__global__ __launch_bounds__(64) void sortfix_kernel(
    float* __restrict__ mst_s, int* __restrict__ dperm,
    const unsigned int* __restrict__ gbase, const unsigned int* __restrict__ btot)
{
    __shared__ float vals[512];
    __shared__ int idxs[512];
    int b = blockIdx.x;
    int base = (int)gbase[b];
    int n = (int)btot[b];
    if (n > 512) n = 512;
    if (n <= 1) return;
    int t = threadIdx.x;
    for (int i = t; i < n; i += 64) { vals[i] = mst_s[base + i]; idxs[i] = dperm[base + i]; }
    __syncthreads();
    for (int i = t; i < n; i += 64) {
        float v = vals[i]; int d = idxs[i];
        int rank = 0;
        for (int j = 0; j < n; ++j) {
            float vj = vals[j];
            rank += (vj < v) || (vj == v && idxs[j] < d);
        }
        mst_s[base + rank] = v;
        dperm[base + rank] = d;
    }
}

// ---------------- K_B: mem_norm (0..511) || query_prep+etab (512..1024) || cq (1025..1152)
__global__ __launch_bounds__(256) void kb_kernel(
    const float* __restrict__ mx, const int* __restrict__ dperm,
    const int* __restrict__ memy,
    char* __restrict__ FK, char* __restrict__ FV, float* __restrict__ y_s,
    const float* __restrict__ feat, const float* __restrict__ keyw,
    const float* __restrict__ keyb, const float* __restrict__ msgw,
    const float* __restrict__ msgb, const float* __restrict__ yemb,
    const int* __restrict__ qrank,
    unsigned short* __restrict__ q2, float* __restrict__ a, float* __restrict__ etab,
    const float* __restrict__ seed_s, const float* __restrict__ mst_s,
    const unsigned int* __restrict__ gbase, const unsigned int* __restrict__ btot,
    int* __restrict__ cq)
{
    __shared__ __align__(16) char smpool[35328];
    const int t = threadIdx.x;
    const int blk = blockIdx.x;

    if (blk < 512) {
        // ----- mem_norm: l2norm gather -> FK/FV fragment-major + y_s -----
        unsigned short* tile = (unsigned short*)smpool;            // [128][132]
        float* rs   = (float*)(smpool + 33792);
        float* invn = (float*)(smpool + 34304);
        int* operm  = (int*)(smpool + 34816);
        const int kb0 = blk * 128;
        const int gt0 = blk * 2;

        if (t < 128) operm[t] = dperm[kb0 + t];
        __syncthreads();
        if (t < 128) y_s[kb0 + t] = (float)memy[operm[t]];

        float4 vals[16];
        #pragma unroll
        for (int i = 0; i < 16; ++i) {
            int f4 = t + 256*i;
            int row = f4 >> 5, col4 = f4 & 31;
            float4 v = *(const float4*)(mx + (size_t)operm[row]*CC + col4*4);
            vals[i] = v;
            float s = v.x*v.x + v.y*v.y + v.z*v.z + v.w*v.w;
            #pragma unroll
            for (int m2 = 1; m2 < 32; m2 <<= 1) s += __shfl_xor(s, m2, 64);
            if ((t & 31) == 0) rs[row] = s;
        }
        __syncthreads();
        if (t < 128) invn[t] = 1.0f / fmaxf(sqrtf(rs[t]), 1e-12f);
        __syncthreads();
        #pragma unroll
        for (int i = 0; i < 16; ++i) {
            int f4 = t + 256*i;
            int row = f4 >> 5, col4 = f4 & 31;
            float sc = invn[row];
            float4 v = vals[i];
            ushort4 o;
            o.x = f2bf(v.x*sc); o.y = f2bf(v.y*sc); o.z = f2bf(v.z*sc); o.w = f2bf(v.w*sc);
            *(ushort4*)&tile[row*132 + col4*4] = o;
        }
        __syncthreads();
        #pragma unroll
        for (int i = 0; i < 8; ++i) {
            int u = t + 256*i;
            int tl = u >> 10;
            int s  = (u >> 8) & 3;
            int cs = (u >> 6) & 3;
            int ln = u & 63;
            int aa = ln & 15, grp = ln >> 4;
            int row = tl*64 + ((s >> 1) << 5) + ((aa & 12) << 1) + ((s & 1) << 2) + (aa & 3);
            int col = cs*32 + grp*8;
            ushort4 p0 = *(ushort4*)&tile[row*132 + col];
            ushort4 p1 = *(ushort4*)&tile[row*132 + col + 4];
            char* dst = FK + ((size_t)(gt0 + tl)*16 + s*4 + cs)*1024 + ln*16;
            *(ushort4*)dst = p0;
            *(ushort4*)(dst + 8) = p1;
        }
        #pragma unroll
        for (int i = 0; i < 8; ++i) {
            int u = t + 256*i;
            int tl = u >> 10;
            int v2 = u & 1023;
            int sc = v2 >> 7;
            int rest = v2 & 127;
            int kk = rest >> 6;
            int ln = rest & 63;
            int c = sc*16 + (ln & 15);
            int key0 = tl*64 + kk*32 + (ln >> 4)*8;
            u32 w0 = (u32)tile[(key0+0)*132 + c] | ((u32)tile[(key0+1)*132 + c] << 16);
            u32 w1 = (u32)tile[(key0+2)*132 + c] | ((u32)tile[(key0+3)*132 + c] << 16);
            u32 w2 = (u32)tile[(key0+4)*132 + c] | ((u32)tile[(key0+5)*132 + c] << 16);
            u32 w3 = (u32)tile[(key0+6)*132 + c] | ((u32)tile[(key0+7)*132 + c] << 16);
            uint4 o; o.x = w0; o.y = w1; o.z = w2; o.w = w3;
            *(uint4*)(FV + ((size_t)(gt0 + tl)*16 + sc*2 + kk)*1024 + ln*16) = o;
        }
    } else if (blk <= 1024) {
        // ----- query_prep (+ etab on blk==1024) -----
        if (blk == 1024) {
            if (t < 128) {
                float acc0 = msgb[t], acc1 = msgb[t];
                for (int c2 = 0; c2 < 128; ++c2) {
                    float w3 = msgw[(256 + c2)*128 + t];
                    acc0 = fmaf(yemb[c2], w3, acc0);
                    acc1 = fmaf(yemb[128 + c2], w3, acc1);
                }
                etab[t] = acc0;
                etab[128 + t] = acc1;
            }
            return;
        }
        float* fl = (float*)smpool;                 // [4][128]
        float* t1 = (float*)(smpool + 2048);        // [4][128]
        const int w = t >> 6;
        const int lane = t & 63;
        const int b = (blk - 512)*4 + w;
        const int j0 = lane, j1 = lane + 64;
        float f0 = feat[b*CC + j0], f1 = feat[b*CC + j1];
        fl[w*128 + j0] = f0; fl[w*128 + j1] = f1;
        float s = f0*f0 + f1*f1;
        #pragma unroll
        for (int m2 = 1; m2 < 64; m2 <<= 1) s += __shfl_xor(s, m2, 64);
        float invn = 1.0f / fmaxf(sqrtf(s), 1e-12f);
        __syncthreads();
        float g0 = 0.f, g1 = 0.f, a0 = 0.f, a1 = 0.f;
        for (int i = 0; i < 128; ++i) {
            float x = fl[w*128 + i];
            g0 = fmaf(x, keyw[i*128 + j0], g0);
            g1 = fmaf(x, keyw[i*128 + j1], g1);
            a0 = fmaf(x, msgw[i*128 + j0], a0);
            a1 = fmaf(x, msgw[i*128 + j1], a1);
        }
        t1[w*128 + j0] = g0*invn + keyb[j0];
        t1[w*128 + j1] = g1*invn + keyb[j1];
        a[b*CC + j0] = a0;
        a[b*CC + j1] = a1;
        __syncthreads();
        float q0 = 0.f, q1 = 0.f;
        for (int c2 = 0; c2 < 128; ++c2) {
            float u = t1[w*128 + c2];
            q0 = fmaf(u, keyw[j0*128 + c2], q0);
            q1 = fmaf(u, keyw[j1*128 + c2], q1);
        }
        const float LOG2E = 1.4426950408889634f;
        int rb = qrank[b];
        q2[rb*CC + j0] = f2bf(q0 * LOG2E);
        q2[rb*CC + j1] = f2bf(q1 * LOG2E);
    } else {
        // ----- cq: 16 queries/block, 16 lanes each -----
        int qi = (blk - 1025)*16 + (t >> 4);
        int l16 = t & 15;
        float s = seed_s[qi];
        int b = bucket_of(s);
        int base = (int)gbase[b];
        int n = (int)btot[b];
        int cnt = 0;
        for (int i = l16; i < n; i += 16) cnt += (mst_s[base + i] <= s) ? 1 : 0;
        #pragma unroll
        for (int m2 = 1; m2 < 16; m2 <<= 1) cnt += __shfl_xor(cnt, m2, 64);
        if (l16 == 0) cq[qi] = base + cnt;
    }
}

// ---------------- flash attention: barrier-free fragment streaming (r12, verified) ----
__global__ __launch_bounds__(256, 4) void attn_kernel(
    const char* __restrict__ FK,
    const char* __restrict__ FV,
    const unsigned short* __restrict__ q2,
    const int* __restrict__ cq,
    const float* __restrict__ y_s,
    unsigned short* __restrict__ Upart,
    float* __restrict__ lpart,
    float* __restrict__ wypart)
{
    __shared__ __align__(16) char bounce[4][4352];   // per-wave transpose bounce

    const int tid = threadIdx.x;
    const int w = tid >> 6;
    const int lane = tid & 63;
    const int g = lane >> 4;
    const int l15 = lane & 15;

    // staircase id -> (qb, chunk): expected-active cells (chunk < 2*(qb+1)) first
    int qb, chunk;
    {
        int id = blockIdx.x;                 // 0..2047 over 32 x 64 cells
        if (id < NACT) {
            int q = 0, base = 0;
            while (id >= base + 2*(q + 1)) { base += 2*(q + 1); ++q; }
            qb = q; chunk = id - base;
        } else {
            int k = id - NACT;
            int q = 0;
            while (k >= 64 - 2*(q + 1)) { k -= 64 - 2*(q + 1); ++q; }
            qb = q; chunk = 2*(q + 1) + k;
        }
    }

    const int cbase = chunk*KCHUNK;
    const int cqmax = cq[qb*QBS + QBS - 1];
    int ntiles = (cqmax - cbase + 63) >> 6;
    if (ntiles <= 0) return;                 // matches final's na predicate exactly
    if (ntiles > KCHUNK/64) ntiles = KCHUNK/64;

    const int qrow0 = qb*QBS + w*16;
    short8 qf[4];
    #pragma unroll
    for (int cs = 0; cs < 4; ++cs)
        qf[cs] = *(const short8*)(q2 + (size_t)(qrow0 + l15)*CC + cs*32 + g*8);
    const int cqv = cq[qrow0 + l15];
    const int g8 = g*8;

    f32x4 accU[8];
    #pragma unroll
    for (int n = 0; n < 8; ++n) accU[n] = (f32x4)0.f;
    float accl = 0.f, accw = 0.f;

    const int gt00 = cbase >> 6;
    for (int kt2 = 0; kt2 < ntiles; ++kt2) {
        const int kb0 = cbase + kt2*64;
        const char* Kf = FK + (size_t)(gt00 + kt2)*16384;
        const char* Vf = FV + (size_t)(gt00 + kt2)*16384;
        const int cut = cqv - kb0;

        u32 pw[8];
        #pragma unroll
        for (int s = 0; s < 4; ++s) {
            f32x4 st = (f32x4)0.f;
            #pragma unroll
            for (int cs = 0; cs < 4; ++cs) {
                short8 kfr = *(const short8*)(Kf + ((s*4 + cs)*64 + lane)*16);
                st = __builtin_amdgcn_mfma_f32_16x16x32_bf16(kfr, qf[cs], st, 0, 0, 0);
            }
            const int kbase = ((s >> 1) << 5) + g8 + ((s & 1) << 2);
            float4 y4 = *(const float4*)(y_s + kb0 + kbase);
            float p0 = (kbase + 0 < cut) ? exp2f(st[0]) : 0.f;
            float p1 = (kbase + 1 < cut) ? exp2f(st[1]) : 0.f;
            float p2 = (kbase + 2 < cut) ? exp2f(st[2]) : 0.f;
            float p3 = (kbase + 3 < cut) ? exp2f(st[3]) : 0.f;
            accl += p0 + p1 + p2 + p3;
            accw = fmaf(p0, y4.x, fmaf(p1, y4.y, fmaf(p2, y4.z, fmaf(p3, y4.w, accw))));
            pw[s*2]     = cvtpk(p0, p1);
            pw[s*2 + 1] = cvtpk(p2, p3);
        }
        u32x4 t0v = {pw[0], pw[1], pw[2], pw[3]};
        u32x4 t1v = {pw[4], pw[5], pw[6], pw[7]};
        short8 pa0 = __builtin_bit_cast(short8, t0v);
        short8 pa1 = __builtin_bit_cast(short8, t1v);

        #pragma unroll
        for (int sc = 0; sc < 8; ++sc) {
            short8 vf0 = *(const short8*)(Vf + ((sc*2 + 0)*64 + lane)*16);
            short8 vf1 = *(const short8*)(Vf + ((sc*2 + 1)*64 + lane)*16);
            accU[sc] = __builtin_amdgcn_mfma_f32_16x16x32_bf16(vf0, pa0, accU[sc], 0, 0, 0);
            accU[sc] = __builtin_amdgcn_mfma_f32_16x16x32_bf16(vf1, pa1, accU[sc], 0, 0, 0);
        }
    }

    // ---- epilogue (per-wave, no block barriers) ----
    const int cell = qb*NSPLIT + chunk;
    accl += __shfl_xor(accl, 16, 64); accl += __shfl_xor(accl, 32, 64);
    accw += __shfl_xor(accw, 16, 64); accw += __shfl_xor(accw, 32, 64);
    if (lane < 16) {
        lpart [cell*QBS + w*16 + lane] = accl;
        wypart[cell*QBS + w*16 + lane] = accw;
    }
    char* bw = bounce[w];
    #pragma unroll
    for (int sc = 0; sc < 8; ++sc) {
        #pragma unroll
        for (int jp = 0; jp < 2; ++jp) {
            u32 pk = cvtpk(accU[sc][2*jp], accU[sc][2*jp + 1]);
            *(u32*)(bw + l15*272 + (sc*16 + g*4 + 2*jp)*2) = pk;
        }
    }
    asm volatile("s_waitcnt lgkmcnt(0)" ::: "memory");
    __builtin_amdgcn_sched_barrier(0);
    #pragma unroll
    for (int p = 0; p < 4; ++p) {
        int seg = p*4 + (lane & 3);
        int q = lane >> 2;
        uint4 v = *(const uint4*)(bw + q*272 + seg*16);
        *(uint4*)((char*)Upart + (size_t)(cell*QBS + w*16 + q)*256 + seg*16) = v;
    }
}

// ---------------- fused combine + epilogue MLP (r12, verified) ------------------------
__global__ __launch_bounds__(256) void final_kernel(
    const float* __restrict__ feat, const unsigned short* __restrict__ Upart,
    const float* __restrict__ lpart, const float* __restrict__ wypart,
    const int* __restrict__ cq,
    const float* __restrict__ a, const float* __restrict__ etab,
    const float* __restrict__ msgw, const int* __restrict__ qperm,
    const float* __restrict__ uw1, const float* __restrict__ ub1,
    const float* __restrict__ uw2, const float* __restrict__ ub2,
    float* __restrict__ out)
{
    __shared__ float fl[4][128], t0[4][128], t1l[4][128];
    const int t = threadIdx.x;
    const int w = t >> 6;
    const int lane = t & 63;
    const int b = blockIdx.x*4 + w;      // sorted row
    const int qb = b >> 6;
    const int cqmax = cq[qb*QBS + QBS - 1];
    int na = (cqmax + KCHUNK - 1) >> 10; // KCHUNK = 1024
    if (na > NSPLIT) na = NSPLIT;        // >= 1 since key 0 always allowed
    const int ob = qperm[b];             // original row
    const int rowin = b & (QBS - 1);
    const int j0 = lane, j1 = lane + 64;
    float f0 = feat[ob*CC + j0], f1 = feat[ob*CC + j1];
    fl[w][j0] = f0; fl[w][j1] = f1;
    float lv = 0.f, wv = 0.f;
    if (lane < na) {
        int o = (qb*NSPLIT + lane)*QBS + rowin;
        lv = lpart[o]; wv = wypart[o];
    }
    #pragma unroll
    for (int m2 = 1; m2 < 64; m2 <<= 1) {
        lv += __shfl_xor(lv, m2, 64);
        wv += __shfl_xor(wv, m2, 64);
    }
    float ua = 0.f, ub = 0.f;
    for (int j = 0; j < na; ++j) {
        const unsigned short* up = Upart + (size_t)((qb*NSPLIT + j)*QBS + rowin)*CC;
        u32 pk = *(const u32*)(up + 2*lane);
        ua += bf2f((unsigned short)(pk & 0xffff));
        ub += bf2f((unsigned short)(pk >> 16));
    }
    t0[w][2*lane] = ua; t0[w][2*lane + 1] = ub;
    __syncthreads();
    float linv = 1.0f / lv;
    float s1 = wv / lv;
    float acc0 = 0.f, acc1 = 0.f;
    for (int i = 0; i < 128; ++i) {
        float x = t0[w][i];
        acc0 = fmaf(x, msgw[(128 + i)*128 + j0], acc0);
        acc1 = fmaf(x, msgw[(128 + i)*128 + j1], acc1);
    }
    float mix0 = (1.f - s1)*etab[j0] + s1*etab[128 + j0];
    float mix1 = (1.f - s1)*etab[j1] + s1*etab[128 + j1];
    float hg0 = a[ob*CC + j0] + acc0*linv + mix0;
    float hg1 = a[ob*CC + j1] + acc1*linv + mix1;
    __syncthreads();
    t0[w][j0] = hg0; t0[w][j1] = hg1;
    __syncthreads();
    float h0 = ub1[j0], h1 = ub1[j1];
    for (int i = 0; i < 128; ++i) {
        float xf = fl[w][i];
        float xh = t0[w][i];
        h0 = fmaf(xf, uw1[i*128 + j0], h0);
        h1 = fmaf(xf, uw1[i*128 + j1], h1);
        h0 = fmaf(xh, uw1[(128 + i)*128 + j0], h0);
        h1 = fmaf(xh, uw1[(128 + i)*128 + j1], h1);
    }
    h0 = fmaxf(h0, 0.f); h1 = fmaxf(h1, 0.f);
    t1l[w][j0] = h0; t1l[w][j1] = h1;
    __syncthreads();
    float o0 = ub2[j0], o1 = ub2[j1];
    for (int i = 0; i < 128; ++i) {
        float x = t1l[w][i];
        o0 = fmaf(x, uw2[i*128 + j0], o0);
        o1 = fmaf(x, uw2[i*128 + j1], o1);
    }
    out[ob*CC + j0] = f0 + o0;
    out[ob*CC + j1] = f1 + o1;
}

extern "C" void kernel_launch(void* const* d_in, const int* in_sizes, int n_in,
                              void* d_out, int out_size, void* d_ws, size_t ws_size,
                              hipStream_t stream) {
    (void)in_sizes; (void)n_in; (void)out_size; (void)ws_size;
    const float* feature  = (const float*)d_in[0];
    const float* memory_x = (const float*)d_in[1];
    const int*   memory_y = (const int*)d_in[2];
    const float* seed_t   = (const float*)d_in[3];
    const float* mem_st   = (const float*)d_in[4];
    const float* key_w    = (const float*)d_in[5];
    const float* key_b    = (const float*)d_in[6];
    const float* msg_w    = (const float*)d_in[7];
    const float* msg_b    = (const float*)d_in[8];
    const float* upd_w1   = (const float*)d_in[9];
    const float* upd_b1   = (const float*)d_in[10];
    const float* upd_w2   = (const float*)d_in[11];
    const float* upd_b2   = (const float*)d_in[12];
    const float* y_emb    = (const float*)d_in[13];
    float* out = (float*)d_out;

    // ---- bump-allocated workspace (256B aligned) ----
    char* ws = (char*)d_ws;
    size_t off = 0;
    auto A = [&](size_t bytes) -> char* {
        char* p = ws + off;
        off += (bytes + 255) & ~(size_t)255;
        return p;
    };
    char* FK = A((size_t)(MM/64)*16*1024);                               // 16.78 MB
    char* FV = A((size_t)(MM/64)*16*1024);                               // 16.78 MB
    unsigned short* q2    = (unsigned short*)A((size_t)BQ*CC*2);         // 512 KB
    float* a      = (float*)A((size_t)BQ*CC*4);                          // 1 MB
    float* etab   = (float*)A(2*CC*4);
    float* lpart  = (float*)A((size_t)NQB*NSPLIT*QBS*4);                 // 512 KB
    float* wypart = (float*)A((size_t)NQB*NSPLIT*QBS*4);                 // 512 KB
    int*   dperm  = (int*)A((size_t)MM*4);                               // 256 KB
    float* mst_s  = (float*)A((size_t)MM*4);                             // 256 KB
    float* y_s    = (float*)A((size_t)MM*4);                             // 256 KB
    unsigned int* btot  = (unsigned int*)A(NBUCKET*4);
    unsigned int* gbase = (unsigned int*)A(NBUCKET*4);
    int*   qperm  = (int*)A(BQ*4);
    int*   qrank  = (int*)A(BQ*4);
    float* seed_s = (float*)A(BQ*4);
    int*   cqbuf  = (int*)A(BQ*4);
    unsigned short* Upart = (unsigned short*)A((size_t)NQB*NSPLIT*QBS*CC*2); // 33.5 MB
    // histT aliases Upart: consumed by sort_scatter before attn writes Upart.
    unsigned int* histT = (unsigned int*)Upart;                          // 1 MB

    ka_kernel<<<512, 256, 0, stream>>>(seed_t, mem_st, qperm, qrank, seed_s, histT);
    sort_scanA_kernel<<<NBUCKET, 64, 0, stream>>>(histT, btot);
    sort_scanB_kernel<<<1, 1024, 0, stream>>>(btot, gbase);
    sort_scatter_kernel<<<MM/256, 256, 0, stream>>>(mem_st, histT, gbase, dperm, mst_s);
    sortfix_kernel<<<NBUCKET, 64, 0, stream>>>(mst_s, dperm, gbase, btot);
    kb_kernel<<<1153, 256, 0, stream>>>(memory_x, dperm, memory_y, FK, FV, y_s,
                                        feature, key_w, key_b, msg_w, msg_b, y_emb,
                                        qrank, q2, a, etab,
                                        seed_s, mst_s, gbase, btot, cqbuf);
    attn_kernel<<<NQB*NSPLIT, 256, 0, stream>>>(FK, FV, q2, cqbuf, y_s,
                                                Upart, lpart, wypart);
    final_kernel<<<BQ/4, 256, 0, stream>>>(feature, Upart, lpart, wypart, cqbuf,
                                           a, etab, msg_w, qperm,
                                           upd_w1, upd_b1, upd_w2, upd_b2, out);
}